// Round 2
// 998.176 us; speedup vs baseline: 1.0554x; 1.0554x over previous
//
#include <hip/hip_runtime.h>
#include <hip/hip_bf16.h>

#define NE 8
#define HID 1024
#define INT_ 4096
#define NTOK 8192
#define CAP 2560

typedef short short8 __attribute__((ext_vector_type(8)));
typedef float floatx4 __attribute__((ext_vector_type(4)));

__device__ __forceinline__ unsigned short f2bf(float f) {
  union { float f; unsigned int u; } v; v.f = f;
  unsigned int u = v.u;
  return (unsigned short)((u + 0x7fffu + ((u >> 16) & 1u)) >> 16);
}

__device__ __forceinline__ void gl2lds16(const void* g, void* l) {
  __builtin_amdgcn_global_load_lds(
      (const __attribute__((address_space(1))) unsigned int*)g,
      (__attribute__((address_space(3))) unsigned int*)l, 16, 0, 0);
}

// ---------------- routing: cumsum position-in-expert ----------------
__global__ void routing_kernel(const int* __restrict__ eidx,
                               int* __restrict__ tfs,
                               int* __restrict__ counts, int* __restrict__ slots) {
  __shared__ unsigned long long masks[128];
  __shared__ int ccnt[128];
  int e = blockIdx.x;
  int tid = threadIdx.x;
  int wave = tid >> 6, lane = tid & 63;

  for (int ch = wave; ch < 128; ch += 4) {
    int t = ch * 64 + lane;
    int2 pr = ((const int2*)eidx)[t];
    bool chosen = (pr.x == e) || (pr.y == e);
    unsigned long long m = __ballot(chosen);
    if (lane == 0) { masks[ch] = m; ccnt[ch] = __popcll(m); }
  }
  __syncthreads();
  if (tid == 0) {
    int run = 0;
    for (int i = 0; i < 128; ++i) { int c = ccnt[i]; ccnt[i] = run; run += c; }
    counts[e] = run < CAP ? run : CAP;
  }
  __syncthreads();
  for (int ch = wave; ch < 128; ch += 4) {
    int t = ch * 64 + lane;
    unsigned long long m = masks[ch];
    if ((m >> lane) & 1ull) {
      int pos = ccnt[ch] + __popcll(m & ((2ull << lane) - 1ull)); // 1-indexed
      int2 pr = ((const int2*)eidx)[t];
      int kk = (pr.x == e) ? 0 : 1;
      if (pos <= CAP) {
        int slot = e * CAP + pos - 1;
        tfs[slot] = t;
        slots[2 * t + kk] = slot;
      } else {
        slots[2 * t + kk] = -1;
      }
    }
  }
}

// ---------------- transpose + fp32->bf16: in [z][R][Cc] -> out [z][Cc][R] ----------------
__global__ void transpose_cvt_kernel(const float* __restrict__ in, unsigned short* __restrict__ out,
                                     int R, int Cc) {
  __shared__ unsigned short tile[64 * 66];
  int z = blockIdx.z;
  int r0 = blockIdx.y * 64, c0 = blockIdx.x * 64;
  const float* inp = in + (size_t)z * R * Cc;
  unsigned short* outp = out + (size_t)z * R * Cc;
  int tx = threadIdx.x & 15, ty = threadIdx.x >> 4;
#pragma unroll
  for (int j = 0; j < 4; ++j) {
    int r = ty + j * 16;
    float4 v = *(const float4*)(inp + (size_t)(r0 + r) * Cc + c0 + 4 * tx);
    tile[r * 66 + 4 * tx + 0] = f2bf(v.x);
    tile[r * 66 + 4 * tx + 1] = f2bf(v.y);
    tile[r * 66 + 4 * tx + 2] = f2bf(v.z);
    tile[r * 66 + 4 * tx + 3] = f2bf(v.w);
  }
  __syncthreads();
#pragma unroll
  for (int j = 0; j < 4; ++j) {
    int c = ty + j * 16;
    ushort4 p;
    p.x = tile[(4 * tx + 0) * 66 + c];
    p.y = tile[(4 * tx + 1) * 66 + c];
    p.z = tile[(4 * tx + 2) * 66 + c];
    p.w = tile[(4 * tx + 3) * 66 + c];
    *(ushort4*)(outp + (size_t)(c0 + c) * R + r0 + 4 * tx) = p;
  }
}

// ---------------- dispatch: gather tokens into (E,C,H) bf16 buffer ----------------
__global__ void dispatch_kernel(const float* __restrict__ x, const int* __restrict__ tfs,
                                const int* __restrict__ counts, unsigned short* __restrict__ ebuf) {
  int slot = blockIdx.x;
  int e = slot / CAP, c = slot - e * CAP;
  bool valid = c < counts[e];
  int t = valid ? tfs[slot] : 0;
  const float4* src = (const float4*)(x + (size_t)t * HID);
  ushort4* dst = (ushort4*)(ebuf + (size_t)slot * HID);
#pragma unroll
  for (int j = 0; j < 2; ++j) {
    int i = threadIdx.x + j * 128;
    ushort4 p;
    if (valid) {
      float4 v = src[i];
      p.x = f2bf(v.x); p.y = f2bf(v.y); p.z = f2bf(v.z); p.w = f2bf(v.w);
    } else {
      p.x = p.y = p.z = p.w = 0;
    }
    dst[i] = p;
  }
}

// ---------------- 256x256 8-phase double-buffered MFMA GEMM ----------------
// A: (E, CAP, KD) bf16 row-major. B: n-major bf16 (rows = output cols, K contiguous).
// GLU: B tile rows 0..127 = gate rows n0.., rows 128..255 = up rows INT_+n0..;
//      out = bf16 silu(gate)*up into (E,CAP,INT_).
// !GLU: B tile rows = wd rows n0..n0+255; out = fp32 into (E,CAP,HID).
// 8 waves; wave w: w_m=w>>2 (rows 64*w_m and 128+64*w_m), w_n=w&3 (cols 32*w_n and 128+32*w_n).
// Quadrant (qm,qn) touches exactly A-half qm / B-half qn for every wave.
// Phase = [ds_read quadrant | stage 1 half-tile | vmcnt(4) | s_barrier | 16 MFMA].
// vmcnt never drains to 0 in the loop (T4); setprio around MFMA (T5).

#define BARX() do { asm volatile("" ::: "memory"); __builtin_amdgcn_s_barrier(); \
  __builtin_amdgcn_sched_barrier(0); asm volatile("" ::: "memory"); } while (0)
#define VMW4() asm volatile("s_waitcnt vmcnt(4)" ::: "memory")

#define STAGE_A(SBUF, HALF, KT) do { \
  _Pragma("unroll") for (int rr = 0; rr < 2; ++rr) { \
    int lrow_ = (HALF) * 128 + rr * 64 + (tid >> 3); \
    int gk_ = (KT) + (((tid & 7) ^ (lrow_ & 7)) << 3); \
    gl2lds16(Ab + (size_t)lrow_ * KD + gk_, \
             (SBUF) + ((HALF) * 128 + rr * 64 + wave * 8) * 64); \
  } } while (0)

#define STAGE_B(SBUF, HALF, KT) do { \
  _Pragma("unroll") for (int rr = 0; rr < 2; ++rr) { \
    int sr_ = rr * 64 + (tid >> 3); \
    int gk_ = (KT) + (((tid & 7) ^ (sr_ & 7)) << 3); \
    gl2lds16(((HALF) ? Bb1 : Bb0) + (size_t)sr_ * KD + gk_, \
             (SBUF) + 16384 + ((HALF) * 128 + rr * 64 + wave * 8) * 64); \
  } } while (0)

#define LDA_Q(SBUF, QM) do { \
  _Pragma("unroll") for (int ml = 0; ml < 4; ++ml) { \
    int rA_ = (QM) * 128 + w_m * 64 + ml * 16 + rl; \
    _Pragma("unroll") for (int ks = 0; ks < 2; ++ks) { \
      int pc_ = (ks * 4 + quad) ^ (rA_ & 7); \
      a[ml][ks] = *(const short8*)((SBUF) + rA_ * 64 + pc_ * 8); \
    } } } while (0)

#define LDB_Q(SBUF, QN, BREG) do { \
  _Pragma("unroll") for (int nl = 0; nl < 2; ++nl) { \
    int rB_ = (QN) * 128 + w_n * 32 + nl * 16 + rl; \
    _Pragma("unroll") for (int ks = 0; ks < 2; ++ks) { \
      int pc_ = (ks * 4 + quad) ^ (rB_ & 7); \
      BREG[nl][ks] = *(const short8*)((SBUF) + 16384 + rB_ * 64 + pc_ * 8); \
    } } } while (0)

#define MFMA_Q(QM, QN, BREG) do { \
  __builtin_amdgcn_s_setprio(1); \
  _Pragma("unroll") for (int ml = 0; ml < 4; ++ml) \
    _Pragma("unroll") for (int nl = 0; nl < 2; ++nl) \
      _Pragma("unroll") for (int ks = 0; ks < 2; ++ks) \
        acc[(QM) * 4 + ml][(QN) * 2 + nl] = __builtin_amdgcn_mfma_f32_16x16x32_bf16( \
            a[ml][ks], BREG[nl][ks], acc[(QM) * 4 + ml][(QN) * 2 + nl], 0, 0, 0); \
  __builtin_amdgcn_s_setprio(0); \
} while (0)

template <int KD, bool GLU>
__global__ __launch_bounds__(512, 2) void gemm256_kernel(
    const unsigned short* __restrict__ A, const unsigned short* __restrict__ B,
    const int* __restrict__ counts, unsigned short* __restrict__ obf,
    float* __restrict__ of) {
  int e = blockIdx.z;
  int c0 = blockIdx.y * 256;
  if (c0 >= counts[e]) return;

  __shared__ alignas(16) unsigned short smem[65536];  // 128 KB: 2 x (A[256][64] + B[256][64])
  unsigned short* s0 = smem;
  unsigned short* s1 = smem + 32768;

  int tid = threadIdx.x;
  int wave = tid >> 6, lane = tid & 63;
  int w_m = wave >> 2, w_n = wave & 3;
  int rl = lane & 15, quad = lane >> 4;

  const unsigned short* Ab = A + ((size_t)e * CAP + c0) * KD;
  const unsigned short* Bb0;
  const unsigned short* Bb1;
  int n0;
  if constexpr (GLU) {
    n0 = blockIdx.x * 128;
    Bb0 = B + ((size_t)e * 2 * INT_ + n0) * KD;          // gate rows
    Bb1 = B + ((size_t)e * 2 * INT_ + INT_ + n0) * KD;   // up rows
  } else {
    n0 = blockIdx.x * 256;
    Bb0 = B + ((size_t)e * HID + n0) * KD;
    Bb1 = Bb0 + (size_t)128 * KD;
  }

  short8 a[4][2], b0[2][2], b1[2][2];
  floatx4 acc[8][4];
#pragma unroll
  for (int i = 0; i < 8; ++i)
#pragma unroll
    for (int j = 0; j < 4; ++j) acc[i][j] = (floatx4){0.f, 0.f, 0.f, 0.f};

  // prologue: tile 0 -> s0, order must match ledger: Ah0, Bh0, Bh1, Ah1
  STAGE_A(s0, 0, 0);
  STAGE_B(s0, 0, 0);
  STAGE_B(s0, 1, 0);
  STAGE_A(s0, 1, 0);
  VMW4();  // guarantees Ah0,Bh0 of tile 0 for P1 reads
  BARX();

  for (int it = 0; it < KD / 128; ++it) {
    int kt1 = it * 128 + 64;                                    // odd tile -> s1
    int ktn = (it * 128 + 128 < KD) ? (it * 128 + 128) : 0;     // next even tile -> s0 (clamped tail restage)
    // P1: reads guaranteed by prev P8 (or prologue) wait
    LDA_Q(s0, 0);
    LDB_Q(s0, 0, b0);
    STAGE_A(s1, 0, kt1);
    VMW4(); BARX();
    MFMA_Q(0, 0, b0);
    // P2
    LDB_Q(s0, 1, b1);
    STAGE_B(s1, 0, kt1);
    VMW4(); BARX();
    MFMA_Q(0, 1, b1);
    // P3 (P4 reads nothing -> no wait)
    LDA_Q(s0, 1);
    STAGE_B(s1, 1, kt1);
    BARX();
    MFMA_Q(1, 1, b1);
    // P4
    STAGE_A(s1, 1, kt1);
    VMW4(); BARX();
    MFMA_Q(1, 0, b0);
    // P5: switch to odd tile in s1; stage next even tile into s0
    LDA_Q(s1, 0);
    LDB_Q(s1, 0, b0);
    STAGE_A(s0, 0, ktn);
    VMW4(); BARX();
    MFMA_Q(0, 0, b0);
    // P6
    LDB_Q(s1, 1, b1);
    STAGE_B(s0, 0, ktn);
    VMW4(); BARX();
    MFMA_Q(0, 1, b1);
    // P7 (P8 reads nothing -> no wait)
    LDA_Q(s1, 1);
    STAGE_B(s0, 1, ktn);
    BARX();
    MFMA_Q(1, 1, b1);
    // P8
    STAGE_A(s0, 1, ktn);
    VMW4(); BARX();
    MFMA_Q(1, 0, b0);
  }
  asm volatile("s_waitcnt vmcnt(0)" ::: "memory");  // drain tail restage before exit

  // epilogue: C layout col=lane&15, row=(lane>>4)*4+reg
#pragma unroll
  for (int mi = 0; mi < 8; ++mi) {
    int row = (mi >> 2) * 128 + w_m * 64 + (mi & 3) * 16 + quad * 4;
    if constexpr (GLU) {
      // gate col j and up col j live in the same thread: acc[mi][nl] / acc[mi][nl+2]
#pragma unroll
      for (int nl = 0; nl < 2; ++nl) {
        int col = n0 + w_n * 32 + nl * 16 + rl;
#pragma unroll
        for (int r = 0; r < 4; ++r) {
          float g = acc[mi][nl][r];
          float u = acc[mi][nl + 2][r];
          float s = g / (1.f + __expf(-g));
          obf[((size_t)e * CAP + c0 + row + r) * INT_ + col] = f2bf(s * u);
        }
      }
    } else {
#pragma unroll
      for (int ni = 0; ni < 4; ++ni) {
        int col = n0 + (ni >> 1) * 128 + w_n * 32 + (ni & 1) * 16 + rl;
#pragma unroll
        for (int r = 0; r < 4; ++r)
          of[((size_t)e * CAP + c0 + row + r) * HID + col] = acc[mi][ni][r];
      }
    }
  }
}

// ---------------- combine: out[t] = sum_k w_k * eout[slot_k] ----------------
__global__ void combine_kernel(const float4* __restrict__ eout, const int* __restrict__ slots,
                               const float* __restrict__ aff, const int* __restrict__ eidx,
                               float4* __restrict__ out) {
  int t = blockIdx.x;
  int i = threadIdx.x;
  int s0 = slots[2 * t], s1 = slots[2 * t + 1];
  int e0 = eidx[2 * t], e1 = eidx[2 * t + 1];
  float a0 = aff[t * NE + e0], a1 = aff[t * NE + e1];
  float inv = 1.f / (a0 + a1);
  float w0 = (s0 >= 0) ? a0 * inv : 0.f;
  float w1 = (s1 >= 0) ? a1 * inv : 0.f;
  int p0 = (s0 >= 0) ? s0 : 0;
  int p1 = (s1 >= 0) ? s1 : 0;
  float4 v0 = eout[(size_t)p0 * 256 + i];
  float4 v1 = eout[(size_t)p1 * 256 + i];
  float4 r;
  r.x = w0 * v0.x + w1 * v1.x;
  r.y = w0 * v0.y + w1 * v1.y;
  r.z = w0 * v0.z + w1 * v1.z;
  r.w = w0 * v0.w + w1 * v1.w;
  out[(size_t)t * 256 + i] = r;
}

extern "C" void kernel_launch(void* const* d_in, const int* in_sizes, int n_in,
                              void* d_out, int out_size, void* d_ws, size_t ws_size,
                              hipStream_t stream) {
  const float* x = (const float*)d_in[0];        // (8192, 1024)
  const float* aff = (const float*)d_in[1];      // (8192, 8)
  const int* eidx = (const int*)d_in[2];         // (8192, 2)
  const float* wgu_f = (const float*)d_in[3];    // (8, 1024, 8192)
  const float* wd_f = (const float*)d_in[4];     // (8, 4096, 1024)
  float* out = (float*)d_out;                    // (8192, 1024)

  char* ws = (char*)d_ws;
  int* tfs = (int*)(ws + 0);                           // int[E*C]      81920 B
  int* counts = (int*)(ws + 163840);                   // int[8]
  int* slots = (int*)(ws + 196608);                    // int[T*2]      65536 B
  unsigned short* ebuf = (unsigned short*)(ws + 262144);      // bf16[8][2560][1024]  ends 42205184
  unsigned short* wgu = (unsigned short*)(ws + 42205184);     // bf16[8][8192][1024]  ends 176422912
  unsigned short* wd = (unsigned short*)(ws + 176422912);     // bf16[8][1024][4096]  ends 243531776
  unsigned short* inter = (unsigned short*)(ws + 243531776);  // bf16[8][2560][4096]  ends 411303936
  // eout aliases wgu's region (wgu dead after gemm1): fp32[8][2560][1024] = 83886080 B < 134217728 B
  float* eout = (float*)(ws + 42205184);

  routing_kernel<<<NE, 256, 0, stream>>>(eidx, tfs, counts, slots);
  transpose_cvt_kernel<<<dim3(128, 16, NE), 256, 0, stream>>>(wgu_f, wgu, 1024, 8192);
  transpose_cvt_kernel<<<dim3(16, 64, NE), 256, 0, stream>>>(wd_f, wd, 4096, 1024);
  dispatch_kernel<<<NE * CAP, 128, 0, stream>>>(x, tfs, counts, ebuf);
  gemm256_kernel<HID, true><<<dim3(32, 10, NE), 512, 0, stream>>>(
      ebuf, wgu, counts, inter, (float*)nullptr);
  gemm256_kernel<INT_, false><<<dim3(4, 10, NE), 512, 0, stream>>>(
      inter, wd, counts, (unsigned short*)nullptr, eout);
  combine_kernel<<<NTOK, 256, 0, stream>>>((const float4*)eout, slots, aff, eidx, (float4*)out);
}